// Round 9
// baseline (617.976 us; speedup 1.0000x reference)
//
#include <hip/hip_runtime.h>

#define N_NODES 50000
#define N_EDGES 800000
#define ND 128
#define ED 32
#define AD 128
#define CAT 288   // 2*ND + ED
#define G3 384    // 3*ND

#define XPAD 296      // LDS row stride (bf16 elems): 592 B, 16B-aligned, ~2-way banks
#define KSTEPS 9      // 288 / 32
#define SCAN_BS 512

typedef unsigned short ushort_t;
typedef __attribute__((ext_vector_type(8))) short bfrag;   // 8 bf16 (4 VGPRs)
typedef __attribute__((ext_vector_type(4))) float f32x4;   // MFMA accumulator

__device__ __forceinline__ unsigned int f2bf(float f) {
    unsigned int u = __float_as_uint(f);
    return (u + 0x7FFFu + ((u >> 16) & 1u)) >> 16;   // RTNE to bf16
}
__device__ __forceinline__ void split2(float a, float b,
                                       unsigned int& hi, unsigned int& lo) {
    const unsigned int ha = f2bf(a), hb = f2bf(b);
    const float ra = a - __uint_as_float(ha << 16);
    const float rb = b - __uint_as_float(hb << 16);
    hi = ha | (hb << 16);
    lo = f2bf(ra) | (f2bf(rb) << 16);
}
__device__ __forceinline__ void split1(float a, ushort_t& hi, ushort_t& lo) {
    const unsigned int ha = f2bf(a);
    const float ra = a - __uint_as_float(ha << 16);
    hi = (ushort_t)ha;
    lo = (ushort_t)f2bf(ra);
}

// ========================= counting sort by dst ============================
__global__ __launch_bounds__(256) void hist_kernel(
    const int* __restrict__ dst, int* __restrict__ deg)
{
    const int e = blockIdx.x * 256 + threadIdx.x;
    if (e < N_EDGES) atomicAdd(&deg[dst[e]], 1);
}

__global__ __launch_bounds__(SCAN_BS) void scan_block_kernel(
    const int* __restrict__ in, int* __restrict__ out,
    int* __restrict__ bsum, int n)
{
    __shared__ int s[SCAN_BS];
    const int g = blockIdx.x * SCAN_BS + threadIdx.x;
    const int v = (g < n) ? in[g] : 0;
    s[threadIdx.x] = v;
    __syncthreads();
    for (int off = 1; off < SCAN_BS; off <<= 1) {
        const int x = (threadIdx.x >= off) ? s[threadIdx.x - off] : 0;
        __syncthreads();
        s[threadIdx.x] += x;
        __syncthreads();
    }
    if (g < n) out[g] = s[threadIdx.x] - v;   // exclusive
    if (threadIdx.x == SCAN_BS - 1) bsum[blockIdx.x] = s[threadIdx.x];
}

__global__ __launch_bounds__(128) void scan_sums_kernel(int* __restrict__ bsum, int nb)
{
    __shared__ int s[128];
    const int i = threadIdx.x;
    s[i] = (i < nb) ? bsum[i] : 0;
    __syncthreads();
    if (i == 0) {
        int acc = 0;
        for (int k = 0; k < nb; ++k) { const int t = s[k]; s[k] = acc; acc += t; }
    }
    __syncthreads();
    if (i < nb) bsum[i] = s[i];
}

__global__ __launch_bounds__(SCAN_BS) void scan_add_kernel(
    int* __restrict__ rowptr, int* __restrict__ cursor,
    const int* __restrict__ bsum, int n)
{
    const int g = blockIdx.x * SCAN_BS + threadIdx.x;
    if (g < n) {
        const int v = rowptr[g] + bsum[blockIdx.x];
        rowptr[g] = v;
        cursor[g] = v;
    }
}

__global__ __launch_bounds__(256) void fill_kernel(
    const int* __restrict__ dst, const int* __restrict__ src,
    int* __restrict__ cursor, int* __restrict__ perm,
    int* __restrict__ src_sorted)
{
    const int e = blockIdx.x * 256 + threadIdx.x;
    if (e < N_EDGES) {
        const int p = atomicAdd(&cursor[dst[e]], 1);
        perm[p] = e;
        src_sorted[p] = src[e];
    }
}

// E[v] = sum of he rows over in-edges of v (round-invariant).
__global__ __launch_bounds__(256) void esum_kernel(
    const float* __restrict__ he, const int* __restrict__ perm,
    const int* __restrict__ rowptr, float* __restrict__ E)
{
    const int id = blockIdx.x * 256 + threadIdx.x;
    if (id >= N_NODES * ED) return;
    const int v = id >> 5, c = id & 31;
    const int r0 = rowptr[v], r1 = rowptr[v + 1];
    float s = 0.f;
    int i = r0;
    for (; i + 4 <= r1; i += 4) {
        const int p0 = perm[i],     p1 = perm[i + 1];
        const int p2 = perm[i + 2], p3 = perm[i + 3];
        const float a = he[(size_t)p0 * ED + c];
        const float b = he[(size_t)p1 * ED + c];
        const float d = he[(size_t)p2 * ED + c];
        const float f = he[(size_t)p3 * ED + c];
        s += (a + b) + (d + f);
    }
    for (; i < r1; ++i)
        s += he[(size_t)perm[i] * ED + c];
    E[(size_t)v * ED + c] = s;
}

// ========================= weight converts (once) ==========================
// W_msg -> fragment-swizzled bf16 hi/lo: [t][nt(8)][ks(9)][kq(4)][lr(16)][j(8)]
__global__ __launch_bounds__(256) void convert_w_kernel(
    const float* __restrict__ W,
    ushort_t* __restrict__ Wm_hi, ushort_t* __restrict__ Wm_lo)
{
    const int id = blockIdx.x * 256 + threadIdx.x;   // 2*36864 = 73728
    if (id >= 2 * 36864) return;
    const int t = id / 36864;
    const int q = id % 36864;
    const int nt = q / 4608,  r1 = q % 4608;
    const int ks = r1 / 512,  r2 = r1 % 512;
    const int kq = r2 / 128,  r3 = r2 % 128;
    const int lr = r3 / 8,    j  = r3 % 8;
    const int n = nt * 16 + lr;
    const int k = ks * 32 + kq * 8 + j;
    const float w = W[(size_t)t * CAT * AD + (size_t)k * AD + n];
    const unsigned int hi = f2bf(w);
    const float r = w - __uint_as_float(hi << 16);
    const size_t o = (size_t)t * 36864 + q;
    Wm_hi[o] = (ushort_t)hi;
    Wm_lo[o] = (ushort_t)f2bf(r);
}

// Gate weights: [t][nt(24)][ks(4)][kq(4)][lr(16)][j(8)]
__global__ __launch_bounds__(256) void convert_gatew_kernel(
    const float* __restrict__ W_ih, const float* __restrict__ W_hh,
    ushort_t* __restrict__ Bih_hi, ushort_t* __restrict__ Bih_lo,
    ushort_t* __restrict__ Bhh_hi, ushort_t* __restrict__ Bhh_lo)
{
    const int id = blockIdx.x * 256 + threadIdx.x;   // 196608
    if (id >= 196608) return;
    const int t   = id / 98304;
    const int rem = id % 98304;
    const int mat = rem / 49152;
    const int q   = rem % 49152;
    const int nt = q / 2048,  r1 = q % 2048;
    const int ks = r1 / 512,  r2 = r1 % 512;
    const int kq = r2 / 128,  r3 = r2 % 128;
    const int lr = r3 / 8,    j  = r3 % 8;
    const int n = nt * 16 + lr;
    const int k = ks * 32 + kq * 8 + j;
    const float* W = mat ? W_hh : W_ih;
    const float w = W[(size_t)t * ND * G3 + (size_t)k * G3 + n];
    const unsigned int hi = f2bf(w);
    const float res = w - __uint_as_float(hi << 16);
    const size_t o = (size_t)t * 49152 + q;
    if (mat) { Bhh_hi[o] = (ushort_t)hi; Bhh_lo[o] = (ushort_t)f2bf(res); }
    else     { Bih_hi[o] = (ushort_t)hi; Bih_lo[o] = (ushort_t)f2bf(res); }
}

// ---------------------------------------------------------------------------
// Fully fused per-round kernel: gather + msg GEMM + GRU + gates.
// NOTE: h_cur and h_out must NOT alias (inter-block WAR race otherwise) —
// caller ping-pongs buffers.
// ---------------------------------------------------------------------------
__global__ __launch_bounds__(256, 3) void fused_round_kernel(
    const float* __restrict__ h_cur, const float* __restrict__ E,
    const int* __restrict__ rowptr, const int* __restrict__ src_sorted,
    const ushort_t* __restrict__ Wm_hi, const ushort_t* __restrict__ Wm_lo,
    const float* __restrict__ bmsg,
    const ushort_t* __restrict__ Bih_hi, const ushort_t* __restrict__ Bih_lo,
    const ushort_t* __restrict__ Bhh_hi, const ushort_t* __restrict__ Bhh_lo,
    const float* __restrict__ b_ih, const float* __restrict__ b_hh,
    float* __restrict__ h_out)
{
    __shared__ ushort_t xh[32 * XPAD];   // 18944 B
    __shared__ ushort_t xl[32 * XPAD];   // 18944 B
    __shared__ float sdeg[32];

    const int t    = threadIdx.x;
    const int wave = t >> 6;
    const int lane = t & 63;
    const int kq   = lane >> 4;
    const int lr   = lane & 15;
    const int n0   = blockIdx.x * 32;

    // ---- phase A: gather S + stage X = [S | h | E] ----
    {
        const int nr = t >> 3, cg = t & 7;           // node-row, 16-col group
        const int n  = min(n0 + nr, N_NODES - 1);
        const int r0 = rowptr[n], r1 = rowptr[n + 1];
        if (cg == 0) sdeg[nr] = (float)(r1 - r0);

        float4 s0 = {0,0,0,0}, s1 = {0,0,0,0}, s2 = {0,0,0,0}, s3 = {0,0,0,0};
        const float4* hv4 = (const float4*)h_cur;
        int i = r0;
        for (; i + 2 <= r1; i += 2) {
            const int sa = src_sorted[i], sb = src_sorted[i + 1];
            const float4* pa = hv4 + (size_t)sa * 32 + cg * 4;
            const float4* pb = hv4 + (size_t)sb * 32 + cg * 4;
            const float4 a0 = pa[0], a1 = pa[1], a2 = pa[2], a3 = pa[3];
            const float4 b0 = pb[0], b1 = pb[1], b2 = pb[2], b3 = pb[3];
            s0.x += a0.x + b0.x; s0.y += a0.y + b0.y; s0.z += a0.z + b0.z; s0.w += a0.w + b0.w;
            s1.x += a1.x + b1.x; s1.y += a1.y + b1.y; s1.z += a1.z + b1.z; s1.w += a1.w + b1.w;
            s2.x += a2.x + b2.x; s2.y += a2.y + b2.y; s2.z += a2.z + b2.z; s2.w += a2.w + b2.w;
            s3.x += a3.x + b3.x; s3.y += a3.y + b3.y; s3.z += a3.z + b3.z; s3.w += a3.w + b3.w;
        }
        if (i < r1) {
            const float4* pa = hv4 + (size_t)src_sorted[i] * 32 + cg * 4;
            const float4 a0 = pa[0], a1 = pa[1], a2 = pa[2], a3 = pa[3];
            s0.x += a0.x; s0.y += a0.y; s0.z += a0.z; s0.w += a0.w;
            s1.x += a1.x; s1.y += a1.y; s1.z += a1.z; s1.w += a1.w;
            s2.x += a2.x; s2.y += a2.y; s2.z += a2.z; s2.w += a2.w;
            s3.x += a3.x; s3.y += a3.y; s3.z += a3.z; s3.w += a3.w;
        }
        uint4 H0, L0, H1, L1;
        split2(s0.x, s0.y, H0.x, L0.x); split2(s0.z, s0.w, H0.y, L0.y);
        split2(s1.x, s1.y, H0.z, L0.z); split2(s1.z, s1.w, H0.w, L0.w);
        split2(s2.x, s2.y, H1.x, L1.x); split2(s2.z, s2.w, H1.y, L1.y);
        split2(s3.x, s3.y, H1.z, L1.z); split2(s3.z, s3.w, H1.w, L1.w);
        *(uint4*)&xh[nr * XPAD + cg * 16]     = H0;
        *(uint4*)&xh[nr * XPAD + cg * 16 + 8] = H1;
        *(uint4*)&xl[nr * XPAD + cg * 16]     = L0;
        *(uint4*)&xl[nr * XPAD + cg * 16 + 8] = L1;

        // h (unscaled) -> cols [128,256)
        {
            const float4* hp = (const float4*)(h_cur + (size_t)n * ND + cg * 16);
            const float4 v0 = hp[0], v1 = hp[1], v2 = hp[2], v3 = hp[3];
            split2(v0.x, v0.y, H0.x, L0.x); split2(v0.z, v0.w, H0.y, L0.y);
            split2(v1.x, v1.y, H0.z, L0.z); split2(v1.z, v1.w, H0.w, L0.w);
            split2(v2.x, v2.y, H1.x, L1.x); split2(v2.z, v2.w, H1.y, L1.y);
            split2(v3.x, v3.y, H1.z, L1.z); split2(v3.z, v3.w, H1.w, L1.w);
            *(uint4*)&xh[nr * XPAD + ND + cg * 16]     = H0;
            *(uint4*)&xh[nr * XPAD + ND + cg * 16 + 8] = H1;
            *(uint4*)&xl[nr * XPAD + ND + cg * 16]     = L0;
            *(uint4*)&xl[nr * XPAD + ND + cg * 16 + 8] = L1;
        }
        // E -> cols [256,288)
        {
            const float4 e4 = *(const float4*)(E + (size_t)n * ED + cg * 4);
            uint2 h2, l2;
            split2(e4.x, e4.y, h2.x, l2.x); split2(e4.z, e4.w, h2.y, l2.y);
            *(uint2*)&xh[nr * XPAD + 2 * ND + cg * 4] = h2;
            *(uint2*)&xl[nr * XPAD + 2 * ND + cg * 4] = l2;
        }
    }
    __syncthreads();

    // ---- phase B: msg MFMA, dual accumulators ----
    f32x4 aS[2][2], aH[2][2];
    #pragma unroll
    for (int m = 0; m < 2; ++m)
        #pragma unroll
        for (int nt = 0; nt < 2; ++nt) {
            aS[m][nt] = (f32x4){0.f, 0.f, 0.f, 0.f};
            aH[m][nt] = (f32x4){0.f, 0.f, 0.f, 0.f};
        }
    float mbias[2];
    #pragma unroll
    for (int nt = 0; nt < 2; ++nt) mbias[nt] = bmsg[wave * 32 + nt * 16 + lr];

    #pragma unroll
    for (int ks = 0; ks < KSTEPS; ++ks) {
        const int ko = ks * 32 + kq * 8;
        const bfrag a0h = *(const bfrag*)&xh[lr * XPAD + ko];
        const bfrag a0l = *(const bfrag*)&xl[lr * XPAD + ko];
        const bfrag a1h = *(const bfrag*)&xh[(16 + lr) * XPAD + ko];
        const bfrag a1l = *(const bfrag*)&xl[(16 + lr) * XPAD + ko];
        const size_t b0 = ((((size_t)(wave * 2 + 0) * 9 + ks) * 4 + kq) * 16 + lr) * 8;
        const size_t b1 = ((((size_t)(wave * 2 + 1) * 9 + ks) * 4 + kq) * 16 + lr) * 8;
        const bfrag w0h = *(const bfrag*)(Wm_hi + b0);
        const bfrag w0l = *(const bfrag*)(Wm_lo + b0);
        const bfrag w1h = *(const bfrag*)(Wm_hi + b1);
        const bfrag w1l = *(const bfrag*)(Wm_lo + b1);
        auto step = [&](f32x4 (&acc)[2][2]) {
            acc[0][0] = __builtin_amdgcn_mfma_f32_16x16x32_bf16(a0h, w0h, acc[0][0], 0, 0, 0);
            acc[0][0] = __builtin_amdgcn_mfma_f32_16x16x32_bf16(a0l, w0h, acc[0][0], 0, 0, 0);
            acc[0][0] = __builtin_amdgcn_mfma_f32_16x16x32_bf16(a0h, w0l, acc[0][0], 0, 0, 0);
            acc[0][1] = __builtin_amdgcn_mfma_f32_16x16x32_bf16(a0h, w1h, acc[0][1], 0, 0, 0);
            acc[0][1] = __builtin_amdgcn_mfma_f32_16x16x32_bf16(a0l, w1h, acc[0][1], 0, 0, 0);
            acc[0][1] = __builtin_amdgcn_mfma_f32_16x16x32_bf16(a0h, w1l, acc[0][1], 0, 0, 0);
            acc[1][0] = __builtin_amdgcn_mfma_f32_16x16x32_bf16(a1h, w0h, acc[1][0], 0, 0, 0);
            acc[1][0] = __builtin_amdgcn_mfma_f32_16x16x32_bf16(a1l, w0h, acc[1][0], 0, 0, 0);
            acc[1][0] = __builtin_amdgcn_mfma_f32_16x16x32_bf16(a1h, w0l, acc[1][0], 0, 0, 0);
            acc[1][1] = __builtin_amdgcn_mfma_f32_16x16x32_bf16(a1h, w1h, acc[1][1], 0, 0, 0);
            acc[1][1] = __builtin_amdgcn_mfma_f32_16x16x32_bf16(a1l, w1h, acc[1][1], 0, 0, 0);
            acc[1][1] = __builtin_amdgcn_mfma_f32_16x16x32_bf16(a1h, w1l, acc[1][1], 0, 0, 0);
        };
        if (ks >= 4 && ks < 8) step(aH); else step(aS);
    }
    __syncthreads();   // X S-column reads complete before aliasing writes

    // ---- phase C: a = accS + deg*(accH + bias) -> a-frags into X S-columns ----
    #pragma unroll
    for (int m = 0; m < 2; ++m) {
        #pragma unroll
        for (int r = 0; r < 4; ++r) {
            const int row = m * 16 + kq * 4 + r;
            const float degf = sdeg[row];
            #pragma unroll
            for (int nt = 0; nt < 2; ++nt) {
                const int c = wave * 32 + nt * 16 + lr;
                const float v = aS[m][nt][r] + degf * (aH[m][nt][r] + mbias[nt]);
                ushort_t h, l;
                split1(v, h, l);
                xh[row * XPAD + c] = h;
                xl[row * XPAD + c] = l;
            }
        }
    }
    __syncthreads();

    // ---- phase D: GRU MFMA, wave-local gate tiles ----
    f32x4 acc_i[2][6], acc_h[2][6];
    #pragma unroll
    for (int m = 0; m < 2; ++m)
        #pragma unroll
        for (int g = 0; g < 6; ++g) {
            acc_i[m][g] = (f32x4){0.f, 0.f, 0.f, 0.f};
            acc_h[m][g] = (f32x4){0.f, 0.f, 0.f, 0.f};
        }

    #pragma unroll
    for (int ks = 0; ks < 4; ++ks) {
        bfrag afh[2], afl[2], hfh[2], hfl[2];
        #pragma unroll
        for (int m = 0; m < 2; ++m) {
            const int ao = (m * 16 + lr) * XPAD + ks * 32 + kq * 8;
            afh[m] = *(const bfrag*)&xh[ao];
            afl[m] = *(const bfrag*)&xl[ao];
            hfh[m] = *(const bfrag*)&xh[ao + ND];
            hfl[m] = *(const bfrag*)&xl[ao + ND];
        }
        #pragma unroll
        for (int lnt = 0; lnt < 6; ++lnt) {
            const int gnt = (lnt >> 1) * 8 + wave * 2 + (lnt & 1);
            const size_t bo = ((((size_t)gnt * 4 + ks) * 4 + kq) * 16 + lr) * 8;
            const bfrag bih_h = *(const bfrag*)(Bih_hi + bo);
            const bfrag bih_l = *(const bfrag*)(Bih_lo + bo);
            const bfrag bhh_h = *(const bfrag*)(Bhh_hi + bo);
            const bfrag bhh_l = *(const bfrag*)(Bhh_lo + bo);
            #pragma unroll
            for (int m = 0; m < 2; ++m) {
                acc_i[m][lnt] = __builtin_amdgcn_mfma_f32_16x16x32_bf16(afh[m], bih_h, acc_i[m][lnt], 0, 0, 0);
                acc_i[m][lnt] = __builtin_amdgcn_mfma_f32_16x16x32_bf16(afl[m], bih_h, acc_i[m][lnt], 0, 0, 0);
                acc_i[m][lnt] = __builtin_amdgcn_mfma_f32_16x16x32_bf16(afh[m], bih_l, acc_i[m][lnt], 0, 0, 0);
                acc_h[m][lnt] = __builtin_amdgcn_mfma_f32_16x16x32_bf16(hfh[m], bhh_h, acc_h[m][lnt], 0, 0, 0);
                acc_h[m][lnt] = __builtin_amdgcn_mfma_f32_16x16x32_bf16(hfl[m], bhh_h, acc_h[m][lnt], 0, 0, 0);
                acc_h[m][lnt] = __builtin_amdgcn_mfma_f32_16x16x32_bf16(hfh[m], bhh_l, acc_h[m][lnt], 0, 0, 0);
            }
        }
    }

    // ---- phase E: gates in registers, h from staged hi+lo ----
    #pragma unroll
    for (int j = 0; j < 2; ++j) {
        const int cj = wave * 32 + j * 16 + lr;
        const float bir = b_ih[cj],       bhr = b_hh[cj];
        const float biz = b_ih[128 + cj], bhz = b_hh[128 + cj];
        const float bin = b_ih[256 + cj], bhn = b_hh[256 + cj];
        #pragma unroll
        for (int m = 0; m < 2; ++m) {
            #pragma unroll
            for (int r = 0; r < 4; ++r) {
                const int row = m * 16 + kq * 4 + r;
                const int node = n0 + row;
                const float rp  = acc_i[m][0 + j][r] + acc_h[m][0 + j][r] + bir + bhr;
                const float zp  = acc_i[m][2 + j][r] + acc_h[m][2 + j][r] + biz + bhz;
                const float inp = acc_i[m][4 + j][r] + bin;
                const float hnp = acc_h[m][4 + j][r] + bhn;
                const float rg = 1.f / (1.f + expf(-rp));
                const float z  = 1.f / (1.f + expf(-zp));
                const float nn = tanhf(inp + rg * hnp);
                const unsigned int hh = xh[row * XPAD + ND + cj];
                const unsigned int hl = xl[row * XPAD + ND + cj];
                const float hval = __uint_as_float(hh << 16) + __uint_as_float(hl << 16);
                if (node < N_NODES)
                    h_out[(size_t)node * ND + cj] = (1.f - z) * nn + z * hval;
            }
        }
    }
}

// ---------------------------------------------------------------------------
extern "C" void kernel_launch(void* const* d_in, const int* in_sizes, int n_in,
                              void* d_out, int out_size, void* d_ws, size_t ws_size,
                              hipStream_t stream)
{
    const float* hv   = (const float*)d_in[0];
    const float* he   = (const float*)d_in[1];
    const int*   src  = (const int*)d_in[2];
    const int*   dst  = (const int*)d_in[3];
    const float* Wmsg = (const float*)d_in[4];
    const float* bmsg = (const float*)d_in[5];
    const float* Wih  = (const float*)d_in[6];
    const float* Whh  = (const float*)d_in[7];
    const float* bih  = (const float*)d_in[8];
    const float* bhh  = (const float*)d_in[9];
    float* out = (float*)d_out;

    const int nscan = ((N_NODES + SCAN_BS - 1) / SCAN_BS) * SCAN_BS;  // 50176
    const int nblk  = nscan / SCAN_BS;                                // 98

    char* p = (char*)d_ws;
    float* h_tmp = (float*)p;                 p += (size_t)N_NODES * ND * 4;   // 25.6 MB
    float* E = (float*)p;                     p += (size_t)N_NODES * ED * 4;   // 6.4 MB
    ushort_t* Wm_hi = (ushort_t*)p;           p += (size_t)2 * 36864 * 2;
    ushort_t* Wm_lo = (ushort_t*)p;           p += (size_t)2 * 36864 * 2;
    ushort_t* Bih_hi = (ushort_t*)p;          p += (size_t)2 * G3 * ND * 2;
    ushort_t* Bih_lo = (ushort_t*)p;          p += (size_t)2 * G3 * ND * 2;
    ushort_t* Bhh_hi = (ushort_t*)p;          p += (size_t)2 * G3 * ND * 2;
    ushort_t* Bhh_lo = (ushort_t*)p;          p += (size_t)2 * G3 * ND * 2;
    int* deg    = (int*)p;                    p += (size_t)nscan * 4;
    int* rowptr = (int*)p;                    p += (size_t)nscan * 4;
    int* cursor = (int*)p;                    p += (size_t)nscan * 4;
    int* bsum   = (int*)p;                    p += 128 * 4;
    int* perm   = (int*)p;                    p += (size_t)N_EDGES * 4;
    int* src_sorted = (int*)p;                p += (size_t)N_EDGES * 4;

    // ---- once per launch: weights, CSR sort, E ----
    convert_w_kernel<<<(2 * 36864 + 255) / 256, 256, 0, stream>>>(Wmsg, Wm_hi, Wm_lo);
    convert_gatew_kernel<<<768, 256, 0, stream>>>(Wih, Whh, Bih_hi, Bih_lo, Bhh_hi, Bhh_lo);

    hipMemsetAsync(deg, 0, (size_t)nscan * 4, stream);
    hist_kernel<<<(N_EDGES + 255) / 256, 256, 0, stream>>>(dst, deg);
    scan_block_kernel<<<nblk, SCAN_BS, 0, stream>>>(deg, rowptr, bsum, nscan);
    scan_sums_kernel<<<1, 128, 0, stream>>>(bsum, nblk);
    scan_add_kernel<<<nblk, SCAN_BS, 0, stream>>>(rowptr, cursor, bsum, nscan);
    fill_kernel<<<(N_EDGES + 255) / 256, 256, 0, stream>>>(dst, src, cursor, perm, src_sorted);
    esum_kernel<<<(N_NODES * ED + 255) / 256, 256, 0, stream>>>(he, perm, rowptr, E);

    const int tile_blocks = (N_NODES + 31) / 32;   // 1563

    // Ping-pong: round 0 hv -> h_tmp, round 1 h_tmp -> out.
    // h_cur never aliases h_out (the fused gather reads h_cur while other
    // blocks write h_out — aliasing would be an inter-block WAR race).
    for (int t = 0; t < 2; ++t) {
        const float* h_cur = (t == 0) ? hv : h_tmp;
        float* h_dst       = (t == 0) ? h_tmp : out;
        fused_round_kernel<<<tile_blocks, 256, 0, stream>>>(
            h_cur, E, rowptr, src_sorted,
            Wm_hi + (size_t)t * 36864, Wm_lo + (size_t)t * 36864,
            bmsg + (size_t)t * AD,
            Bih_hi + (size_t)t * G3 * ND, Bih_lo + (size_t)t * G3 * ND,
            Bhh_hi + (size_t)t * G3 * ND, Bhh_lo + (size_t)t * G3 * ND,
            bih + (size_t)t * G3, bhh + (size_t)t * G3, h_dst);
    }
}